// Round 9
// baseline (1129.602 us; speedup 1.0000x reference)
//
#include <hip/hip_runtime.h>
#include <hip/hip_bf16.h>

#define NWIN   4096
#define NTOK   49
#define CDIM   384
#define NHEAD  12
#define QKVN   1152

typedef __attribute__((ext_vector_type(8))) short bf16x8;
typedef __attribute__((ext_vector_type(4))) short bf16x4;
typedef __attribute__((ext_vector_type(4))) float f32x4;
typedef __attribute__((ext_vector_type(2))) unsigned int u32x2;
typedef unsigned int u32;
typedef unsigned short u16;

static __device__ __forceinline__ u16 f2bf(float f) {
  union { float f; u32 u; } w; w.f = f;
  u32 r = w.u + 0x7fffu + ((w.u >> 16) & 1u);
  return (u16)(r >> 16);
}
static __device__ __forceinline__ float blo(u32 v) {
  union { u32 u; float f; } w; w.u = v << 16; return w.f;
}
static __device__ __forceinline__ float bhi(u32 v) {
  union { u32 u; float f; } w; w.u = v & 0xffff0000u; return w.f;
}
static __device__ __forceinline__ u32 cvtpk2(float lo, float hi) {
  u32 r; asm("v_cvt_pk_bf16_f32 %0, %1, %2" : "=v"(r) : "v"(lo), "v"(hi));
  return r;
}
static __device__ __forceinline__ void gld_lds16(const u16* g, u16* l) {
  __builtin_amdgcn_global_load_lds((const __attribute__((address_space(1))) u32*)g,
                                   (__attribute__((address_space(3))) u32*)l, 16, 0, 0);
}

// ---- prep: weights -> bf16, packed rel_bias gather ----
__global__ void k_prep(const float* __restrict__ qkv_w, const float* __restrict__ proj_w,
                       const float* __restrict__ btab, const int* __restrict__ ridx,
                       u16* __restrict__ wq, u16* __restrict__ wp, u32* __restrict__ rbp)
{
  const int n1 = QKVN * CDIM;
  const int n2 = CDIM * CDIM;
  const int n3 = NHEAD * NTOK * 26;
  for (int i = blockIdx.x * blockDim.x + threadIdx.x; i < n1 + n2 + n3;
       i += gridDim.x * blockDim.x) {
    if (i < n1) {
      wq[i] = f2bf(qkv_w[i]);
    } else if (i < n1 + n2) {
      wp[i - n1] = f2bf(proj_w[i - n1]);
    } else {
      int t = i - n1 - n2;
      int h = t / (NTOK * 26); int rem = t % (NTOK * 26);
      int r = rem / 26, p = rem % 26;
      float lo = 0.f, hi = 0.f;
      if (p < 25) {
        lo = btab[ridx[r * NTOK + 2 * p] * NHEAD + h];
        if (2 * p + 1 < NTOK) hi = btab[ridx[r * NTOK + 2 * p + 1] * NHEAD + h];
      }
      rbp[(h * NTOK + r) * 26 + p] = (u32)f2bf(lo) | ((u32)f2bf(hi) << 16);
    }
  }
}

// ---- 128x128 GEMM, T2 swizzle + XCD chunking.
//      A_FP32: A read as fp32, reg-staged + cvt_pk + swizzled ds_write (fuses convx);
//              A-loads for tile t+1 issue before compute(t) (T14 overlap).
//      else:   A via pre-swizzled gld_lds (round-8 path). B always gld_lds. ----
template<bool A_FP32, bool OUT_BF16>
__global__ __launch_bounds__(256, 4)
void k_gemm(const void* __restrict__ Ap, int lda,
            const u16* __restrict__ Bt, const float* __restrict__ bias,
            void* __restrict__ C, int ldc, int K, int tiles_n)
{
  __shared__ alignas(16) u16 As[128 * 64];
  __shared__ alignas(16) u16 Bs[128 * 64];
  const int tid = threadIdx.x;
  const int w = tid >> 6, l = tid & 63;

  // bijective XCD-chunk swizzle (m204)
  const int nwg = (int)gridDim.x;
  const int xcd = (int)blockIdx.x & 7, idx8 = (int)blockIdx.x >> 3;
  const int q8 = nwg >> 3, r8w = nwg & 7;
  const int lid = (xcd < r8w ? xcd * (q8 + 1) : r8w * (q8 + 1) + (xcd - r8w) * q8) + idx8;

  const int tm = lid / tiles_n, tn = lid % tiles_n;
  const int wm = (w >> 1) * 64, wn = (w & 1) * 64;
  const long arow0 = (long)tm * 128;
  const long brow0 = (long)tn * 128;
  const int r8 = l >> 3;                      // row within 8-row staging chunk
  const int c8e = (l & 7) * 8;                // unswizzled col (elems)
  const int swp = ((l & 7) ^ r8) * 8;         // pre-swizzled source col (gld_lds)

  const float* Af = (const float*)Ap;
  const u16*   Ab = (const u16*)Ap;

  float4 arf[4][2];                           // in-flight A tile (fp32 path)
  auto issueA = [&](int kk) {
#pragma unroll
    for (int q = 0; q < 4; ++q) {
      const float* src = Af + (arow0 + w * 32 + q * 8 + r8) * (long)lda + kk + c8e;
      arf[q][0] = *(const float4*)src;
      arf[q][1] = *(const float4*)(src + 4);
    }
  };

  f32x4 acc[4][4];
  const f32x4 z = {0.f, 0.f, 0.f, 0.f};
#pragma unroll
  for (int m = 0; m < 4; ++m)
#pragma unroll
    for (int n = 0; n < 4; ++n) acc[m][n] = z;

  if (A_FP32) issueA(0);

  for (int kk = 0; kk < K; kk += 64) {
    __syncthreads();                          // all readers done with As/Bs
#pragma unroll
    for (int q = 0; q < 4; ++q) {
      int ra = w * 32 + q * 8;
      gld_lds16(Bt + (brow0 + ra + r8) * (long)K + kk + swp, &Bs[ra * 64]);
      if (!A_FP32)
        gld_lds16(Ab + (arow0 + ra + r8) * (long)lda + kk + swp, &As[ra * 64]);
    }
    if (A_FP32) {
      // write current A tile (waits on arf regs), then prefetch next
#pragma unroll
      for (int q = 0; q < 4; ++q) {
        uint4 v;
        v.x = cvtpk2(arf[q][0].x, arf[q][0].y);
        v.y = cvtpk2(arf[q][0].z, arf[q][0].w);
        v.z = cvtpk2(arf[q][1].x, arf[q][1].y);
        v.w = cvtpk2(arf[q][1].z, arf[q][1].w);
        *(uint4*)&As[(w * 32 + q * 8 + r8) * 64 + swp] = v;
      }
      if (kk + 64 < K) issueA(kk + 64);       // overlaps compute below
    }
    __syncthreads();                          // drains gld_lds + ds_writes
#pragma unroll
    for (int ks = 0; ks < 2; ++ks) {
      const int ko = ks * 32 + (l >> 4) * 8;
      const int rl = l & 15;
      const int sa = (rl & 7) * 8;            // read-side XOR
      bf16x8 af[4], bfr[4];
#pragma unroll
      for (int m = 0; m < 4; ++m) af[m]  = *(const bf16x8*)&As[(wm + m * 16 + rl) * 64 + (ko ^ sa)];
#pragma unroll
      for (int n = 0; n < 4; ++n) bfr[n] = *(const bf16x8*)&Bs[(wn + n * 16 + rl) * 64 + (ko ^ sa)];
      // SWAPPED: D regs walk Bt-row (N), D lane&15 = A-row (M)
#pragma unroll
      for (int m = 0; m < 4; ++m)
#pragma unroll
        for (int n = 0; n < 4; ++n)
          acc[m][n] = __builtin_amdgcn_mfma_f32_16x16x32_bf16(bfr[n], af[m], acc[m][n], 0, 0, 0);
    }
  }

  // epilogue: lane owns one M row per m-frag; regs = 4 consecutive N
  const int li = l & 15, g4 = (l >> 4) * 4;
  float4 bv[4];
#pragma unroll
  for (int n = 0; n < 4; ++n)
    bv[n] = *(const float4*)&bias[tn * 128 + wn + n * 16 + g4];
#pragma unroll
  for (int m = 0; m < 4; ++m) {
    const long row = arow0 + wm + m * 16 + li;
#pragma unroll
    for (int n = 0; n < 4; ++n) {
      const long colb = brow0 + wn + n * 16 + g4;
      float v0 = acc[m][n][0] + bv[n].x;
      float v1 = acc[m][n][1] + bv[n].y;
      float v2 = acc[m][n][2] + bv[n].z;
      float v3 = acc[m][n][3] + bv[n].w;
      if (OUT_BF16) {
        u32x2 pk;
        pk[0] = (u32)f2bf(v0) | ((u32)f2bf(v1) << 16);
        pk[1] = (u32)f2bf(v2) | ((u32)f2bf(v3) << 16);
        *(u32x2*)((u16*)C + row * ldc + colb) = pk;
      } else {
        float4 pk; pk.x = v0; pk.y = v1; pk.z = v2; pk.w = v3;
        *(float4*)((float*)C + row * ldc + colb) = pk;
      }
    }
  }
}

// ---- MFMA attention (unchanged from passing round 8) ----
__global__ __launch_bounds__(384, 2)
void k_attn(u16* __restrict__ qkv, const float* __restrict__ maskc,
            const u32* __restrict__ rbp)
{
  __shared__ alignas(16) u16 Vt[6][32 * 64];
  __shared__ alignas(16) u32 mp[NTOK * 26];
  const int tid = threadIdx.x;
  const int w = tid >> 6, l = tid & 63;
  const int g = l >> 4, li = l & 15;
  const int id = blockIdx.x;
  const int logical = (id & 7) * ((int)gridDim.x >> 3) + (id >> 3);
  const int bl = logical >> 1, hg = logical & 1;
  const int h = hg * 6 + w;
  const long rowbase = (long)bl * NTOK;
  const float scale = 0.17677669529663687f;

  u16* vt = Vt[w];
  {
    const int jj = l >> 2;
    const int d0 = (l & 3) * 8;
#pragma unroll
    for (int it = 0; it < 4; ++it) {
      int j = it * 16 + jj;
      bf16x8 vv = {0, 0, 0, 0, 0, 0, 0, 0};
      if (j < NTOK)
        vv = *(const bf16x8*)(qkv + (rowbase + j) * QKVN + 2 * CDIM + h * 32 + d0);
#pragma unroll
      for (int t = 0; t < 8; ++t)
        vt[(d0 + t) * 64 + (j ^ (t << 3))] = (u16)vv[t];
    }
  }
  for (int e = tid; e < NTOK * 25; e += 384) {
    int i = e / 25, p = e - i * 25;
    const float* mrow = maskc + (long)bl * (NTOK * NTOK) + i * NTOK;
    float lo = mrow[2 * p];
    float hi = (2 * p + 1 < NTOK) ? mrow[2 * p + 1] : 0.f;
    mp[i * 26 + p] = (u32)f2bf(lo) | ((u32)f2bf(hi) << 16);
  }
  if (tid < NTOK) mp[tid * 26 + 25] = 0;
  __syncthreads();

  bf16x8 kf[4], qf[4];
#pragma unroll
  for (int jm = 0; jm < 4; ++jm) {
    int rj = jm * 16 + li; if (rj >= NTOK) rj = NTOK - 1;
    kf[jm] = *(const bf16x8*)(qkv + (rowbase + rj) * QKVN + CDIM + h * 32 + g * 8);
  }
#pragma unroll
  for (int in = 0; in < 4; ++in) {
    int ri = in * 16 + li; if (ri >= NTOK) ri = NTOK - 1;
    qf[in] = *(const bf16x8*)(qkv + (rowbase + ri) * QKVN + h * 32 + g * 8);
  }
  const f32x4 z = {0.f, 0.f, 0.f, 0.f};
  f32x4 st[4][4];
#pragma unroll
  for (int jm = 0; jm < 4; ++jm)
#pragma unroll
    for (int in = 0; in < 4; ++in)
      st[jm][in] = __builtin_amdgcn_mfma_f32_16x16x32_bf16(kf[jm], qf[in], z, 0, 0, 0);

#pragma unroll
  for (int jm = 0; jm < 4; ++jm) {
    int p0 = 8 * jm + 2 * g; if (p0 > 24) p0 = 24;
#pragma unroll
    for (int in = 0; in < 4; ++in) {
      int i = 16 * in + li; int ic = i < NTOK ? i : NTOK - 1;
      const u32* bp = rbp + (h * NTOK + ic) * 26 + p0;
      u32 b0w = bp[0], b1w = bp[1];
      u32 m0w = mp[ic * 26 + p0], m1w = mp[ic * 26 + p0 + 1];
      st[jm][in][0] = st[jm][in][0] * scale + blo(b0w) + blo(m0w);
      st[jm][in][1] = st[jm][in][1] * scale + bhi(b0w) + bhi(m0w);
      st[jm][in][2] = st[jm][in][2] * scale + blo(b1w) + blo(m1w);
      st[jm][in][3] = st[jm][in][3] * scale + bhi(b1w) + bhi(m1w);
    }
  }

  float inv[4];
#pragma unroll
  for (int in = 0; in < 4; ++in) {
    float mx = -3.0e38f;
#pragma unroll
    for (int jm = 0; jm < 4; ++jm)
#pragma unroll
      for (int rr = 0; rr < 4; ++rr) mx = fmaxf(mx, st[jm][in][rr]);
    mx = fmaxf(mx, __shfl_xor(mx, 16));
    mx = fmaxf(mx, __shfl_xor(mx, 32));
    float sum = 0.f;
#pragma unroll
    for (int jm = 0; jm < 4; ++jm) {
      const int j0 = 16 * jm + 4 * g;
#pragma unroll
      for (int rr = 0; rr < 4; ++rr) {
        float p = (j0 + rr < NTOK) ? __expf(st[jm][in][rr] - mx) : 0.f;
        st[jm][in][rr] = p; sum += p;
      }
    }
    sum += __shfl_xor(sum, 16);
    sum += __shfl_xor(sum, 32);
    inv[in] = (16 * in + li < NTOK) ? (1.f / sum) : 0.f;
  }

  f32x4 oacc[4][2];
#pragma unroll
  for (int im = 0; im < 4; ++im)
#pragma unroll
    for (int dn = 0; dn < 2; ++dn) oacc[im][dn] = z;
  const int sw = (li & 7) << 3;
#pragma unroll
  for (int ks = 0; ks < 2; ++ks) {
    union { bf16x4 h[2]; bf16x8 v8; } vf[2];
#pragma unroll
    for (int dn = 0; dn < 2; ++dn) {
      const u16* vrow = &vt[(16 * dn + li) * 64];
      vf[dn].h[0] = *(const bf16x4*)&vrow[(32 * ks + 4 * g) ^ sw];
      vf[dn].h[1] = *(const bf16x4*)&vrow[(32 * ks + 16 + 4 * g) ^ sw];
    }
#pragma unroll
    for (int im = 0; im < 4; ++im) {
      union { u32 w[4]; bf16x8 v8; } pa;
      pa.w[0] = cvtpk2(st[2 * ks][im][0] * inv[im], st[2 * ks][im][1] * inv[im]);
      pa.w[1] = cvtpk2(st[2 * ks][im][2] * inv[im], st[2 * ks][im][3] * inv[im]);
      pa.w[2] = cvtpk2(st[2 * ks + 1][im][0] * inv[im], st[2 * ks + 1][im][1] * inv[im]);
      pa.w[3] = cvtpk2(st[2 * ks + 1][im][2] * inv[im], st[2 * ks + 1][im][3] * inv[im]);
#pragma unroll
      for (int dn = 0; dn < 2; ++dn)
        oacc[im][dn] = __builtin_amdgcn_mfma_f32_16x16x32_bf16(pa.v8, vf[dn].v8, oacc[im][dn], 0, 0, 0);
    }
  }

#pragma unroll
  for (int im = 0; im < 4; ++im) {
#pragma unroll
    for (int rr = 0; rr < 4; ++rr) {
      const int i = 16 * im + 4 * g + rr;
      if (i < NTOK) {
        u16* orow = qkv + (rowbase + i) * QKVN + h * 32;
#pragma unroll
        for (int dn = 0; dn < 2; ++dn)
          orow[16 * dn + li] = f2bf(oacc[im][dn][rr]);
      }
    }
  }
}

// ---------------- host ----------------
extern "C" void kernel_launch(void* const* d_in, const int* in_sizes, int n_in,
                              void* d_out, int out_size, void* d_ws, size_t ws_size,
                              hipStream_t stream)
{
  const float* x      = (const float*)d_in[0];
  const float* mask   = (const float*)d_in[1];
  const float* qkv_w  = (const float*)d_in[2];
  const float* qkv_b  = (const float*)d_in[3];
  const float* proj_w = (const float*)d_in[4];
  const float* proj_b = (const float*)d_in[5];
  const float* btab   = (const float*)d_in[6];
  const int*   ridx   = (const int*)d_in[7];
  float* out = (float*)d_out;

  auto need = [](int bc) -> size_t {
    return (size_t)bc * NTOK * QKVN * 2      // qkv buffer (bf16)
         + (size_t)QKVN * CDIM * 2
         + (size_t)CDIM * CDIM * 2
         + (size_t)NHEAD * NTOK * 26 * 4
         + 1024;
  };
  int BC = NWIN;
  while (BC > 128 && need(BC) > ws_size) BC >>= 1;

  char* p = (char*)d_ws;
  u16* qkvbuf = (u16*)p;  p += (size_t)BC * NTOK * QKVN * 2;
  u16* wq     = (u16*)p;  p += (size_t)QKVN * CDIM * 2;
  u16* wp     = (u16*)p;  p += (size_t)CDIM * CDIM * 2;
  u32* rbp    = (u32*)p;

  k_prep<<<512, 256, 0, stream>>>(qkv_w, proj_w, btab, ridx, wq, wp, rbp);

  const int nc = NWIN / BC;
  const int Mc = BC * NTOK;
  for (int c = 0; c < nc; ++c) {
    const float* xc = x + (size_t)c * Mc * CDIM;
    k_gemm<true, true><<<(Mc / 128) * 9, 256, 0, stream>>>(
        (const void*)xc, CDIM, wq, qkv_b, (void*)qkvbuf, QKVN, CDIM, 9);
    k_attn<<<BC * 2, 384, 0, stream>>>(
        qkvbuf, mask + (size_t)c * BC * NTOK * NTOK, rbp);
    k_gemm<false, false><<<(Mc / 128) * 3, 256, 0, stream>>>(
        (const void*)qkvbuf, QKVN, wp, proj_b, (void*)(out + (size_t)c * Mc * CDIM), CDIM, CDIM, 3);
  }
}

// Round 10
// 802.241 us; speedup vs baseline: 1.4081x; 1.4081x over previous
//
#include <hip/hip_runtime.h>
#include <hip/hip_bf16.h>

#define NWIN   4096
#define NTOK   49
#define CDIM   384
#define NHEAD  12
#define QKVN   1152

typedef __attribute__((ext_vector_type(8))) short bf16x8;
typedef __attribute__((ext_vector_type(4))) short bf16x4;
typedef __attribute__((ext_vector_type(4))) float f32x4;
typedef __attribute__((ext_vector_type(2))) unsigned int u32x2;
typedef unsigned int u32;
typedef unsigned short u16;

static __device__ __forceinline__ u16 f2bf(float f) {
  union { float f; u32 u; } w; w.f = f;
  u32 r = w.u + 0x7fffu + ((w.u >> 16) & 1u);
  return (u16)(r >> 16);
}
static __device__ __forceinline__ float blo(u32 v) {
  union { u32 u; float f; } w; w.u = v << 16; return w.f;
}
static __device__ __forceinline__ float bhi(u32 v) {
  union { u32 u; float f; } w; w.u = v & 0xffff0000u; return w.f;
}
static __device__ __forceinline__ u32 cvtpk2(float lo, float hi) {
  u32 r; asm("v_cvt_pk_bf16_f32 %0, %1, %2" : "=v"(r) : "v"(lo), "v"(hi));
  return r;
}
static __device__ __forceinline__ void gld_lds16(const u16* g, u16* l) {
  __builtin_amdgcn_global_load_lds((const __attribute__((address_space(1))) u32*)g,
                                   (__attribute__((address_space(3))) u32*)l, 16, 0, 0);
}

// ---- prep: weights -> bf16, packed rel_bias gather ----
__global__ void k_prep(const float* __restrict__ qkv_w, const float* __restrict__ proj_w,
                       const float* __restrict__ btab, const int* __restrict__ ridx,
                       u16* __restrict__ wq, u16* __restrict__ wp, u32* __restrict__ rbp)
{
  const int n1 = QKVN * CDIM;
  const int n2 = CDIM * CDIM;
  const int n3 = NHEAD * NTOK * 26;
  for (int i = blockIdx.x * blockDim.x + threadIdx.x; i < n1 + n2 + n3;
       i += gridDim.x * blockDim.x) {
    if (i < n1) {
      wq[i] = f2bf(qkv_w[i]);
    } else if (i < n1 + n2) {
      wp[i - n1] = f2bf(proj_w[i - n1]);
    } else {
      int t = i - n1 - n2;
      int h = t / (NTOK * 26); int rem = t % (NTOK * 26);
      int r = rem / 26, p = rem % 26;
      float lo = 0.f, hi = 0.f;
      if (p < 25) {
        lo = btab[ridx[r * NTOK + 2 * p] * NHEAD + h];
        if (2 * p + 1 < NTOK) hi = btab[ridx[r * NTOK + 2 * p + 1] * NHEAD + h];
      }
      rbp[(h * NTOK + r) * 26 + p] = (u32)f2bf(lo) | ((u32)f2bf(hi) << 16);
    }
  }
}

// ---------------- x fp32 -> bf16 ----------------
__global__ void k_convx(const float* __restrict__ x, u16* __restrict__ xb, long n8)
{
  long i = (long)blockIdx.x * blockDim.x + threadIdx.x;
  long stride = (long)gridDim.x * blockDim.x;
  for (; i < n8; i += stride) {
    const float4* p = (const float4*)x + i * 2;
    float4 a = p[0], b = p[1];
    u32 w0 = (u32)f2bf(a.x) | ((u32)f2bf(a.y) << 16);
    u32 w1 = (u32)f2bf(a.z) | ((u32)f2bf(a.w) << 16);
    u32 w2 = (u32)f2bf(b.x) | ((u32)f2bf(b.y) << 16);
    u32 w3 = (u32)f2bf(b.z) | ((u32)f2bf(b.w) << 16);
    uint4 v; v.x = w0; v.y = w1; v.z = w2; v.w = w3;
    ((uint4*)xb)[i] = v;
  }
}

// ---- 128x128 GEMM, T2 swizzle + XCD chunking + double-buffered LDS pipeline:
//      stage(t+1) issued BEFORE compute(t); single __syncthreads per K-step
//      (its vmcnt(0) drain lands after compute -> load latency hidden). ----
template<bool OUT_BF16>
__global__ __launch_bounds__(256, 2)
void k_gemm(const u16* __restrict__ A, int lda,
            const u16* __restrict__ Bt, const float* __restrict__ bias,
            void* __restrict__ C, int ldc, int K, int tiles_n)
{
  __shared__ alignas(16) u16 As[2][128 * 64];
  __shared__ alignas(16) u16 Bs[2][128 * 64];
  const int tid = threadIdx.x;
  const int w = tid >> 6, l = tid & 63;

  // bijective XCD-chunk swizzle (m204)
  const int nwg = (int)gridDim.x;
  const int xcd = (int)blockIdx.x & 7, idx8 = (int)blockIdx.x >> 3;
  const int q8 = nwg >> 3, r8w = nwg & 7;
  const int lid = (xcd < r8w ? xcd * (q8 + 1) : r8w * (q8 + 1) + (xcd - r8w) * q8) + idx8;

  const int tm = lid / tiles_n, tn = lid % tiles_n;
  const int wm = (w >> 1) * 64, wn = (w & 1) * 64;
  const long arow0 = (long)tm * 128;
  const long brow0 = (long)tn * 128;
  const int r8 = l >> 3;                      // row within 8-row staging chunk
  const int swp = ((l & 7) ^ r8) * 8;         // pre-swizzled source col (elems)

  auto stage = [&](int kk, int buf) {
#pragma unroll
    for (int q = 0; q < 4; ++q) {
      int ra = w * 32 + q * 8;
      gld_lds16(A  + (arow0 + ra + r8) * (long)lda + kk + swp, &As[buf][ra * 64]);
      gld_lds16(Bt + (brow0 + ra + r8) * (long)K   + kk + swp, &Bs[buf][ra * 64]);
    }
  };

  f32x4 acc[4][4];
  const f32x4 z = {0.f, 0.f, 0.f, 0.f};
#pragma unroll
  for (int m = 0; m < 4; ++m)
#pragma unroll
    for (int n = 0; n < 4; ++n) acc[m][n] = z;

  stage(0, 0);
  __syncthreads();                            // drain prologue loads

  int cur = 0;
  for (int kk = 0; kk < K; kk += 64) {
    if (kk + 64 < K) stage(kk + 64, cur ^ 1); // prefetch next tile (other buffer)
#pragma unroll
    for (int ks = 0; ks < 2; ++ks) {
      const int ko = ks * 32 + (l >> 4) * 8;
      const int rl = l & 15;
      const int sa = (rl & 7) * 8;            // read-side XOR
      bf16x8 af[4], bfr[4];
#pragma unroll
      for (int m = 0; m < 4; ++m) af[m]  = *(const bf16x8*)&As[cur][(wm + m * 16 + rl) * 64 + (ko ^ sa)];
#pragma unroll
      for (int n = 0; n < 4; ++n) bfr[n] = *(const bf16x8*)&Bs[cur][(wn + n * 16 + rl) * 64 + (ko ^ sa)];
      // SWAPPED: D regs walk Bt-row (N), D lane&15 = A-row (M)
#pragma unroll
      for (int m = 0; m < 4; ++m)
#pragma unroll
        for (int n = 0; n < 4; ++n)
          acc[m][n] = __builtin_amdgcn_mfma_f32_16x16x32_bf16(bfr[n], af[m], acc[m][n], 0, 0, 0);
    }
    __syncthreads();                          // drains prefetch, next buf ready
    cur ^= 1;
  }

  // epilogue: lane owns one M row per m-frag; regs = 4 consecutive N
  const int li = l & 15, g4 = (l >> 4) * 4;
  float4 bv[4];
#pragma unroll
  for (int n = 0; n < 4; ++n)
    bv[n] = *(const float4*)&bias[tn * 128 + wn + n * 16 + g4];
#pragma unroll
  for (int m = 0; m < 4; ++m) {
    const long row = arow0 + wm + m * 16 + li;
#pragma unroll
    for (int n = 0; n < 4; ++n) {
      const long colb = brow0 + wn + n * 16 + g4;
      float v0 = acc[m][n][0] + bv[n].x;
      float v1 = acc[m][n][1] + bv[n].y;
      float v2 = acc[m][n][2] + bv[n].z;
      float v3 = acc[m][n][3] + bv[n].w;
      if (OUT_BF16) {
        u32x2 pk;
        pk[0] = (u32)f2bf(v0) | ((u32)f2bf(v1) << 16);
        pk[1] = (u32)f2bf(v2) | ((u32)f2bf(v3) << 16);
        *(u32x2*)((u16*)C + row * ldc + colb) = pk;
      } else {
        float4 pk; pk.x = v0; pk.y = v1; pk.z = v2; pk.w = v3;
        *(float4*)((float*)C + row * ldc + colb) = pk;
      }
    }
  }
}

// ---- MFMA attention (unchanged from passing round 8) ----
__global__ __launch_bounds__(384, 2)
void k_attn(u16* __restrict__ qkv, const float* __restrict__ maskc,
            const u32* __restrict__ rbp)
{
  __shared__ alignas(16) u16 Vt[6][32 * 64];
  __shared__ alignas(16) u32 mp[NTOK * 26];
  const int tid = threadIdx.x;
  const int w = tid >> 6, l = tid & 63;
  const int g = l >> 4, li = l & 15;
  const int id = blockIdx.x;
  const int logical = (id & 7) * ((int)gridDim.x >> 3) + (id >> 3);
  const int bl = logical >> 1, hg = logical & 1;
  const int h = hg * 6 + w;
  const long rowbase = (long)bl * NTOK;
  const float scale = 0.17677669529663687f;

  u16* vt = Vt[w];
  {
    const int jj = l >> 2;
    const int d0 = (l & 3) * 8;
#pragma unroll
    for (int it = 0; it < 4; ++it) {
      int j = it * 16 + jj;
      bf16x8 vv = {0, 0, 0, 0, 0, 0, 0, 0};
      if (j < NTOK)
        vv = *(const bf16x8*)(qkv + (rowbase + j) * QKVN + 2 * CDIM + h * 32 + d0);
#pragma unroll
      for (int t = 0; t < 8; ++t)
        vt[(d0 + t) * 64 + (j ^ (t << 3))] = (u16)vv[t];
    }
  }
  for (int e = tid; e < NTOK * 25; e += 384) {
    int i = e / 25, p = e - i * 25;
    const float* mrow = maskc + (long)bl * (NTOK * NTOK) + i * NTOK;
    float lo = mrow[2 * p];
    float hi = (2 * p + 1 < NTOK) ? mrow[2 * p + 1] : 0.f;
    mp[i * 26 + p] = (u32)f2bf(lo) | ((u32)f2bf(hi) << 16);
  }
  if (tid < NTOK) mp[tid * 26 + 25] = 0;
  __syncthreads();

  bf16x8 kf[4], qf[4];
#pragma unroll
  for (int jm = 0; jm < 4; ++jm) {
    int rj = jm * 16 + li; if (rj >= NTOK) rj = NTOK - 1;
    kf[jm] = *(const bf16x8*)(qkv + (rowbase + rj) * QKVN + CDIM + h * 32 + g * 8);
  }
#pragma unroll
  for (int in = 0; in < 4; ++in) {
    int ri = in * 16 + li; if (ri >= NTOK) ri = NTOK - 1;
    qf[in] = *(const bf16x8*)(qkv + (rowbase + ri) * QKVN + h * 32 + g * 8);
  }
  const f32x4 z = {0.f, 0.f, 0.f, 0.f};
  f32x4 st[4][4];
#pragma unroll
  for (int jm = 0; jm < 4; ++jm)
#pragma unroll
    for (int in = 0; in < 4; ++in)
      st[jm][in] = __builtin_amdgcn_mfma_f32_16x16x32_bf16(kf[jm], qf[in], z, 0, 0, 0);

#pragma unroll
  for (int jm = 0; jm < 4; ++jm) {
    int p0 = 8 * jm + 2 * g; if (p0 > 24) p0 = 24;
#pragma unroll
    for (int in = 0; in < 4; ++in) {
      int i = 16 * in + li; int ic = i < NTOK ? i : NTOK - 1;
      const u32* bp = rbp + (h * NTOK + ic) * 26 + p0;
      u32 b0w = bp[0], b1w = bp[1];
      u32 m0w = mp[ic * 26 + p0], m1w = mp[ic * 26 + p0 + 1];
      st[jm][in][0] = st[jm][in][0] * scale + blo(b0w) + blo(m0w);
      st[jm][in][1] = st[jm][in][1] * scale + bhi(b0w) + bhi(m0w);
      st[jm][in][2] = st[jm][in][2] * scale + blo(b1w) + blo(m1w);
      st[jm][in][3] = st[jm][in][3] * scale + bhi(b1w) + bhi(m1w);
    }
  }

  float inv[4];
#pragma unroll
  for (int in = 0; in < 4; ++in) {
    float mx = -3.0e38f;
#pragma unroll
    for (int jm = 0; jm < 4; ++jm)
#pragma unroll
      for (int rr = 0; rr < 4; ++rr) mx = fmaxf(mx, st[jm][in][rr]);
    mx = fmaxf(mx, __shfl_xor(mx, 16));
    mx = fmaxf(mx, __shfl_xor(mx, 32));
    float sum = 0.f;
#pragma unroll
    for (int jm = 0; jm < 4; ++jm) {
      const int j0 = 16 * jm + 4 * g;
#pragma unroll
      for (int rr = 0; rr < 4; ++rr) {
        float p = (j0 + rr < NTOK) ? __expf(st[jm][in][rr] - mx) : 0.f;
        st[jm][in][rr] = p; sum += p;
      }
    }
    sum += __shfl_xor(sum, 16);
    sum += __shfl_xor(sum, 32);
    inv[in] = (16 * in + li < NTOK) ? (1.f / sum) : 0.f;
  }

  f32x4 oacc[4][2];
#pragma unroll
  for (int im = 0; im < 4; ++im)
#pragma unroll
    for (int dn = 0; dn < 2; ++dn) oacc[im][dn] = z;
  const int sw = (li & 7) << 3;
#pragma unroll
  for (int ks = 0; ks < 2; ++ks) {
    union { bf16x4 h[2]; bf16x8 v8; } vf[2];
#pragma unroll
    for (int dn = 0; dn < 2; ++dn) {
      const u16* vrow = &vt[(16 * dn + li) * 64];
      vf[dn].h[0] = *(const bf16x4*)&vrow[(32 * ks + 4 * g) ^ sw];
      vf[dn].h[1] = *(const bf16x4*)&vrow[(32 * ks + 16 + 4 * g) ^ sw];
    }
#pragma unroll
    for (int im = 0; im < 4; ++im) {
      union { u32 w[4]; bf16x8 v8; } pa;
      pa.w[0] = cvtpk2(st[2 * ks][im][0] * inv[im], st[2 * ks][im][1] * inv[im]);
      pa.w[1] = cvtpk2(st[2 * ks][im][2] * inv[im], st[2 * ks][im][3] * inv[im]);
      pa.w[2] = cvtpk2(st[2 * ks + 1][im][0] * inv[im], st[2 * ks + 1][im][1] * inv[im]);
      pa.w[3] = cvtpk2(st[2 * ks + 1][im][2] * inv[im], st[2 * ks + 1][im][3] * inv[im]);
#pragma unroll
      for (int dn = 0; dn < 2; ++dn)
        oacc[im][dn] = __builtin_amdgcn_mfma_f32_16x16x32_bf16(pa.v8, vf[dn].v8, oacc[im][dn], 0, 0, 0);
    }
  }

#pragma unroll
  for (int im = 0; im < 4; ++im) {
#pragma unroll
    for (int rr = 0; rr < 4; ++rr) {
      const int i = 16 * im + 4 * g + rr;
      if (i < NTOK) {
        u16* orow = qkv + (rowbase + i) * QKVN + h * 32;
#pragma unroll
        for (int dn = 0; dn < 2; ++dn)
          orow[16 * dn + li] = f2bf(oacc[im][dn][rr]);
      }
    }
  }
}

// ---------------- host ----------------
extern "C" void kernel_launch(void* const* d_in, const int* in_sizes, int n_in,
                              void* d_out, int out_size, void* d_ws, size_t ws_size,
                              hipStream_t stream)
{
  const float* x      = (const float*)d_in[0];
  const float* mask   = (const float*)d_in[1];
  const float* qkv_w  = (const float*)d_in[2];
  const float* qkv_b  = (const float*)d_in[3];
  const float* proj_w = (const float*)d_in[4];
  const float* proj_b = (const float*)d_in[5];
  const float* btab   = (const float*)d_in[6];
  const int*   ridx   = (const int*)d_in[7];
  float* out = (float*)d_out;

  auto need = [](int bc) -> size_t {
    return (size_t)bc * NTOK * QKVN * 2
         + (size_t)bc * NTOK * CDIM * 2
         + (size_t)QKVN * CDIM * 2
         + (size_t)CDIM * CDIM * 2
         + (size_t)NHEAD * NTOK * 26 * 4
         + 1024;
  };
  int BC = NWIN;
  while (BC > 128 && need(BC) > ws_size) BC >>= 1;

  char* p = (char*)d_ws;
  u16* qkvbuf = (u16*)p;  p += (size_t)BC * NTOK * QKVN * 2;
  u16* xb     = (u16*)p;  p += (size_t)BC * NTOK * CDIM * 2;
  u16* wq     = (u16*)p;  p += (size_t)QKVN * CDIM * 2;
  u16* wp     = (u16*)p;  p += (size_t)CDIM * CDIM * 2;
  u32* rbp    = (u32*)p;

  k_prep<<<512, 256, 0, stream>>>(qkv_w, proj_w, btab, ridx, wq, wp, rbp);

  const int nc = NWIN / BC;
  const int Mc = BC * NTOK;
  for (int c = 0; c < nc; ++c) {
    const float* xc = x + (size_t)c * Mc * CDIM;
    k_convx<<<2048, 256, 0, stream>>>(xc, xb, (long)Mc * CDIM / 8);
    k_gemm<true><<<(Mc / 128) * 9, 256, 0, stream>>>(
        xb, CDIM, wq, qkv_b, (void*)qkvbuf, QKVN, CDIM, 9);
    k_attn<<<BC * 2, 384, 0, stream>>>(
        qkvbuf, mask + (size_t)c * BC * NTOK * NTOK, rbp);
    k_gemm<false><<<(Mc / 128) * 3, 256, 0, stream>>>(
        qkvbuf, QKVN, wp, proj_b, (void*)(out + (size_t)c * Mc * CDIM), CDIM, CDIM, 3);
  }
}